// Round 5
// baseline (1400.823 us; speedup 1.0000x reference)
//
#include <hip/hip_runtime.h>

#define NB 256            // blocks (1 per CU)
#define BT 1024           // threads per block (16 waves) — halves per-thread data
#define MSTEPS 8
// Fixed problem shape: L = 500000.
#define CHUNK 1954        // ceil(500000 / NB) rows per block
#define REGT 8            // register-resident rows per octet (8*128 = 1024 rows)
#define REGL (REGT * 128)
#define LDSROWS (CHUNK - REGL)   // 930 rows resident in LDS (dense 128 B rows)

typedef float v4f __attribute__((ext_vector_type(4)));

struct PParams {
  const float* candidate;
  const float* z_past;
  const float* q_w; const float* q_b;
  const float* k_w; const float* k_b;
  const float* v_w; const float* v_b;
  const float* o_w; const float* o_b;
  const float* rel_bias;
  const float* coupling;
  const float* norm_scale;
  float* out;
  float* ws;   // [0..15] uint barrier state (memset to 0 each launch); [16..] 2*132*NB partials
  int L;
};

__device__ __forceinline__ float mish_f(float x) {
  float sp = fmaxf(x, 0.0f) + log1pf(expf(-fabsf(x)));
  return x * tanhf(sp);
}

// Recompute q projection, folded score vectors a_h (pre-scaled by inv_sqrt_d=0.5),
// and the l<64 relative-bias delta table, from the current state sZ.
// Must be called by ALL threads of the block (contains barriers).
__device__ void compute_qar(const PParams& p, int tid,
                            float* sZ, float* sQ, float* sA, float* sRel) {
  if (tid < 32) {
    float acc = p.q_b[tid];
    const float* row = p.q_w + tid * 32;
    #pragma unroll
    for (int c = 0; c < 32; ++c) acc = fmaf(row[c], sZ[c], acc);
    sQ[tid] = acc;
  }
  __syncthreads();
  if (tid < 128) {
    int h = tid >> 5, c = tid & 31;
    float acc = 0.f;
    #pragma unroll
    for (int jj = 0; jj < 8; ++jj)
      acc = fmaf(sQ[8 * h + jj], p.k_w[(8 * h + jj) * 32 + c], acc);
    sA[tid] = 0.5f * acc;               // fold inv_sqrt_d
  }
  if (tid >= 256 && tid < 512) {       // BT=1024: bound the rel-bias writers to 256 lanes
    // rel-bias delta vs the saturated idx=128 entry (constant part cancels in softmax)
    int t = tid - 256;
    int l = t >> 2, h = t & 3;
    float acc = 0.f;
    #pragma unroll
    for (int jj = 0; jj < 8; ++jj) {
      int jidx = 8 * h + jj;
      acc = fmaf(sQ[jidx],
                 p.rel_bias[(l + 64) * 32 + jidx] - p.rel_bias[128 * 32 + jidx],
                 acc);
    }
    sRel[t] = 0.5f * acc;
  }
  __syncthreads();
}

// Minimal grid barrier: one release-add per block, relaxed spin on a flag,
// agent fences at the edges. Counters zeroed by hipMemsetAsync each launch.
__device__ __forceinline__ void grid_barrier(float* wsf, int iter, int tid) {
  unsigned* sync = reinterpret_cast<unsigned*>(wsf);
  __syncthreads();
  __threadfence();                     // release block's partial-table stores
  if (tid == 0) {
    unsigned* cnt = sync + 2 * iter;
    unsigned* flg = sync + 2 * iter + 1;
    unsigned old = __hip_atomic_fetch_add(cnt, 1u, __ATOMIC_RELEASE,
                                          __HIP_MEMORY_SCOPE_AGENT);
    if (old == (unsigned)(NB - 1)) {
      __hip_atomic_store(flg, 1u, __ATOMIC_RELEASE, __HIP_MEMORY_SCOPE_AGENT);
    } else {
      while (__hip_atomic_load(flg, __ATOMIC_RELAXED,
                               __HIP_MEMORY_SCOPE_AGENT) == 0u)
        __builtin_amdgcn_s_sleep(4);   // ~256-cycle poll granularity
    }
  }
  __syncthreads();
  __threadfence();                     // acquire: invalidate stale caches before reads
}

// One l-row contribution (octet scheme: 8 lanes own one 32-float row, 4 floats each).
// All values SSA / constant-indexed.
__device__ __forceinline__ void trip_body(const v4f (&A)[4], v4f zv,
                                          const float* sRel, bool dorel, int relrow,
                                          v4f (&S)[4], v4f& Zc) {
  float d0 = 0.f, d1 = 0.f, d2 = 0.f, d3 = 0.f;
  #pragma unroll
  for (int k = 0; k < 4; ++k) {
    d0 = fmaf(A[0][k], zv[k], d0);
    d1 = fmaf(A[1][k], zv[k], d1);
    d2 = fmaf(A[2][k], zv[k], d2);
    d3 = fmaf(A[3][k], zv[k], d3);
  }
  // complete the 32-wide dot across the 8-lane octet
  d0 += __shfl_xor(d0, 1); d0 += __shfl_xor(d0, 2); d0 += __shfl_xor(d0, 4);
  d1 += __shfl_xor(d1, 1); d1 += __shfl_xor(d1, 2); d1 += __shfl_xor(d1, 4);
  d2 += __shfl_xor(d2, 1); d2 += __shfl_xor(d2, 2); d2 += __shfl_xor(d2, 4);
  d3 += __shfl_xor(d3, 1); d3 += __shfl_xor(d3, 2); d3 += __shfl_xor(d3, 4);
  if (dorel) {
    const float4 r = reinterpret_cast<const float4*>(sRel)[relrow];
    d0 += r.x; d1 += r.y; d2 += r.z; d3 += r.w;
  }
  float w0 = __expf(d0), w1 = __expf(d1), w2 = __expf(d2), w3 = __expf(d3);
  Zc[0] += w0; Zc[1] += w1; Zc[2] += w2; Zc[3] += w3;
  S[0] += zv * w0;
  S[1] += zv * w1;
  S[2] += zv * w2;
  S[3] += zv * w3;
}

// Design point: 1 block/CU (LDS-capped), 16 waves/CU, VGPR demand ~95 < the
// 128-VGPR budget the compiler insists on (rounds 1-4: all launch-bounds
// variants pinned at 128 and spilled). This plan fits UNDER 128 -> no spill.
__global__ __attribute__((amdgpu_flat_work_group_size(BT, BT)))
void photonic_kernel(PParams p) {
  __shared__ float sZ[32];
  __shared__ float sQ[32];
  __shared__ float sOutV[32];
  __shared__ float sZn[32];
  __shared__ __align__(16) float sA[128];     // a[h][c]
  __shared__ __align__(16) float sRel[256];   // relT[l][h], l<64
  __shared__ float sRed[BT / 64][8][20];      // per-wave reduced (S[4][4] + Z[4]) per octet-slot
  __shared__ float sSS[128];                  // global-reduced S[h][c]
  __shared__ float sSZ[4];                    // global-reduced Z[h]
  __shared__ __align__(16) float sZp[LDSROWS * 32];  // LDS-resident z rows (dense 128 B)

  const int tid  = threadIdx.x;
  const int b    = blockIdx.x;
  const int o    = tid & 7;        // lane-slot within octet (owns cols [4o, 4o+4))
  const int oct  = tid >> 3;       // octet index 0..127
  const int wave = tid >> 6;       // 0..15
  const int lane = tid & 63;

  const int chunk0 = b * CHUNK;
  const int clen   = min(CHUNK, p.L - chunk0);          // 1954, last block 1730
  const int ldsl   = min(clen - REGL, (int)LDSROWS);    // 930, last block 706

  // init state z = candidate (real-interleaved flat 32)
  if (tid < 32) sZ[tid] = p.candidate[tid];
  __syncthreads();
  compute_qar(p, tid, sZ, sQ, sA, sRel);

  // Register-resident slice of z_past: rows chunk0 + oct + t*128, t < REGT.
  v4f zr0, zr1, zr2, zr3, zr4, zr5, zr6, zr7;

  for (int iter = 0; iter < MSTEPS; ++iter) {
    // stage my 4-column slice of a[h][*] into registers
    v4f A[4];
    #pragma unroll
    for (int h = 0; h < 4; ++h)
      A[h] = *reinterpret_cast<const v4f*>(sA + h * 32 + o * 4);

    v4f S[4];
    #pragma unroll
    for (int h = 0; h < 4; ++h) S[h] = 0.f;
    v4f Zc = 0.f;

    if (iter == 0) {
      // ---- first pass: load from HBM, populate registers + LDS, and compute ----
      #define LOADROW(t, dst)                                                   \
        {                                                                       \
          dst = *reinterpret_cast<const v4f*>(                                  \
              p.z_past + (size_t)(chunk0 + oct + ((t) << 7)) * 32 + o * 4);     \
          trip_body(A, dst, sRel, (b == 0) && ((t) == 0) && (oct < 64), oct,    \
                    S, Zc);                                                     \
        }
      LOADROW(0, zr0)  LOADROW(1, zr1)  LOADROW(2, zr2)  LOADROW(3, zr3)
      LOADROW(4, zr4)  LOADROW(5, zr5)  LOADROW(6, zr6)  LOADROW(7, zr7)
      #undef LOADROW
      #pragma unroll
      for (int t = 0; t < 8; ++t) {
        int li = oct + (t << 7);
        if (li < ldsl) {
          v4f zv = *reinterpret_cast<const v4f*>(
              p.z_past + (size_t)(chunk0 + REGL + li) * 32 + o * 4);
          *reinterpret_cast<v4f*>(sZp + li * 32 + o * 4) = zv;
          trip_body(A, zv, sRel, false, 0, S, Zc);
        }
      }
    } else {
      // ---- steady state: zero global traffic; registers + LDS only ----
      #define COMPROW(t, src)                                                   \
        trip_body(A, src, sRel, (b == 0) && ((t) == 0) && (oct < 64), oct, S,   \
                  Zc);
      COMPROW(0, zr0)  COMPROW(1, zr1)  COMPROW(2, zr2)  COMPROW(3, zr3)
      COMPROW(4, zr4)  COMPROW(5, zr5)  COMPROW(6, zr6)  COMPROW(7, zr7)
      #undef COMPROW
      #pragma unroll
      for (int t = 0; t < 8; ++t) {
        int li = oct + (t << 7);
        if (li < ldsl) {
          v4f zv = *reinterpret_cast<const v4f*>(sZp + li * 32 + o * 4);
          trip_body(A, zv, sRel, false, 0, S, Zc);
        }
      }
    }

    // reduce across the 8 octets of each wave (lane&7 == o is preserved)
    #pragma unroll
    for (int m = 8; m <= 32; m <<= 1) {
      #pragma unroll
      for (int h = 0; h < 4; ++h) {
        #pragma unroll
        for (int k = 0; k < 4; ++k) S[h][k] += __shfl_xor(S[h][k], m);
        Zc[h] += __shfl_xor(Zc[h], m);
      }
    }
    if (lane < 8) {  // lanes 0..7: lane == o
      #pragma unroll
      for (int h = 0; h < 4; ++h) {
        #pragma unroll
        for (int k = 0; k < 4; ++k) sRed[wave][lane][h * 4 + k] = S[h][k];
        sRed[wave][lane][16 + h] = Zc[h];
      }
    }
    __syncthreads();

    // per-block partials -> global, component-major [comp][block] for coalesced reduce
    float* part = p.ws + 16 + (iter & 1) * (132 * NB);
    if (tid < 132) {
      float acc = 0.f;
      if (tid < 128) {
        int h = tid >> 5, c = tid & 31;
        int jj = c >> 2, k = c & 3;
        #pragma unroll
        for (int w2 = 0; w2 < BT / 64; ++w2) acc += sRed[w2][jj][h * 4 + k];
        part[(h * 33 + c) * NB + b] = acc;
      } else {
        int h = tid - 128;
        #pragma unroll
        for (int w2 = 0; w2 < BT / 64; ++w2) acc += sRed[w2][0][16 + h];
        part[(h * 33 + 32) * NB + b] = acc;
      }
    }

    grid_barrier(p.ws, iter, tid);

    // every block redundantly reduces all partials (135 KB, L2/L3-resident)
    if (tid < 132) {
      const float4* pp = reinterpret_cast<const float4*>(part + tid * NB);
      float acc = 0.f;
      for (int i = 0; i < NB / 4; ++i) {
        float4 v4 = pp[i];
        acc += (v4.x + v4.y) + (v4.z + v4.w);
      }
      int h = tid / 33, k = tid % 33;
      if (k < 32) sSS[h * 32 + k] = acc; else sSZ[h] = acc;
    }
    __syncthreads();

    // out_flat[j'] = v_w[j',:] @ (S_h / Z_h) + v_b[j']   (h = j'>>3)
    if (tid < 32) {
      int h = tid >> 3;
      float acc = 0.f;
      const float* row = p.v_w + tid * 32;
      #pragma unroll
      for (int c = 0; c < 32; ++c) acc = fmaf(row[c], sSS[h * 32 + c], acc);
      sOutV[tid] = acc / sSZ[h] + p.v_b[tid];
    }
    __syncthreads();
    // mod = o_w @ out + o_b ; z += coupling*mod ; mish
    if (tid < 32) {
      float acc = p.o_b[tid];
      const float* row = p.o_w + tid * 32;
      #pragma unroll
      for (int c = 0; c < 32; ++c) acc = fmaf(row[c], sOutV[c], acc);
      float zv2 = sZ[tid] + p.coupling[0] * acc;
      sZn[tid] = mish_f(zv2);
    }
    __syncthreads();
    // layer-norm over the 16 real / 16 imag components separately
    if (tid < 32) {
      int par = tid & 1;
      float m = 0.f;
      #pragma unroll
      for (int e = 0; e < 16; ++e) m += sZn[2 * e + par];
      m *= (1.f / 16.f);
      float v = 0.f;
      #pragma unroll
      for (int e = 0; e < 16; ++e) { float dd = sZn[2 * e + par] - m; v = fmaf(dd, dd, v); }
      v *= (1.f / 16.f);
      sZ[tid] = (sZn[tid] - m) * rsqrtf(v + 1e-5f) * p.norm_scale[0];
    }
    __syncthreads();

    if (iter != MSTEPS - 1) {
      compute_qar(p, tid, sZ, sQ, sA, sRel);
    } else {
      if (b == 0 && tid < 32) p.out[tid] = sZ[tid];
    }
  }
}

extern "C" void kernel_launch(void* const* d_in, const int* in_sizes, int n_in,
                              void* d_out, int out_size, void* d_ws, size_t ws_size,
                              hipStream_t stream) {
  PParams p;
  p.candidate  = (const float*)d_in[0];
  p.z_past     = (const float*)d_in[1];
  p.q_w = (const float*)d_in[2];  p.q_b = (const float*)d_in[3];
  p.k_w = (const float*)d_in[4];  p.k_b = (const float*)d_in[5];
  p.v_w = (const float*)d_in[6];  p.v_b = (const float*)d_in[7];
  p.o_w = (const float*)d_in[8];  p.o_b = (const float*)d_in[9];
  p.rel_bias   = (const float*)d_in[10];
  p.coupling   = (const float*)d_in[11];
  p.norm_scale = (const float*)d_in[12];
  p.out = (float*)d_out;
  p.ws  = (float*)d_ws;
  p.L   = in_sizes[1] / 32;

  // zero the 16 barrier words (captured as a graph node -> re-zeroed every replay)
  hipMemsetAsync(d_ws, 0, 64, stream);

  void* args[] = { &p };
  hipLaunchCooperativeKernel((const void*)photonic_kernel,
                             dim3(NB), dim3(BT), args, 0, stream);
}

// Round 6
// 825.080 us; speedup vs baseline: 1.6978x; 1.6978x over previous
//
#include <hip/hip_runtime.h>

#define NB 256            // blocks (1 per CU)
#define BT 512            // threads per block (8 waves) — the no-spill config (r0: 96 VGPR)
#define MSTEPS 8
// Fixed problem shape: L = 500000.
#define CHUNK 1954        // ceil(500000 / NB) rows per block
#define LDSR 1120         // rows resident in LDS (dense 128 B rows, 143 KB)

typedef float v8f __attribute__((ext_vector_type(8)));
typedef float v4f __attribute__((ext_vector_type(4)));

struct PParams {
  const float* candidate;
  const float* z_past;
  const float* q_w; const float* q_b;
  const float* k_w; const float* k_b;
  const float* v_w; const float* v_b;
  const float* o_w; const float* o_b;
  const float* rel_bias;
  const float* coupling;
  const float* norm_scale;
  float* out;
  float* ws;   // [0..15] uint barrier state (memset each launch); [16..] 2*132*NB partials
  int L;
};

__device__ __forceinline__ float mish_f(float x) {
  float sp = fmaxf(x, 0.0f) + log1pf(expf(-fabsf(x)));
  return x * tanhf(sp);
}

// Recompute q projection, folded score vectors a_h (pre-scaled by inv_sqrt_d=0.5),
// and the l<64 relative-bias delta table, from the current state sZ.
// Must be called by ALL threads of the block (contains barriers).
__device__ void compute_qar(const PParams& p, int tid,
                            float* sZ, float* sQ, float* sA, float* sRel) {
  if (tid < 32) {
    float acc = p.q_b[tid];
    const float* row = p.q_w + tid * 32;
    #pragma unroll
    for (int c = 0; c < 32; ++c) acc = fmaf(row[c], sZ[c], acc);
    sQ[tid] = acc;
  }
  __syncthreads();
  if (tid < 128) {
    int h = tid >> 5, c = tid & 31;
    float acc = 0.f;
    #pragma unroll
    for (int jj = 0; jj < 8; ++jj)
      acc = fmaf(sQ[8 * h + jj], p.k_w[(8 * h + jj) * 32 + c], acc);
    sA[tid] = 0.5f * acc;               // fold inv_sqrt_d
  }
  if (tid >= 256) {
    // rel-bias delta vs the saturated idx=128 entry (constant part cancels in softmax)
    int t = tid - 256;
    int l = t >> 2, h = t & 3;
    float acc = 0.f;
    #pragma unroll
    for (int jj = 0; jj < 8; ++jj) {
      int jidx = 8 * h + jj;
      acc = fmaf(sQ[jidx],
                 p.rel_bias[(l + 64) * 32 + jidx] - p.rel_bias[128 * 32 + jidx],
                 acc);
    }
    sRel[t] = 0.5f * acc;
  }
  __syncthreads();
}

// Minimal grid barrier: one release-add per block, relaxed spin on a flag,
// agent fences at the edges. Counters zeroed by hipMemsetAsync each launch.
__device__ __forceinline__ void grid_barrier(float* wsf, int iter, int tid) {
  unsigned* sync = reinterpret_cast<unsigned*>(wsf);
  __syncthreads();
  __threadfence();                     // release block's partial-table stores
  if (tid == 0) {
    unsigned* cnt = sync + 2 * iter;
    unsigned* flg = sync + 2 * iter + 1;
    unsigned old = __hip_atomic_fetch_add(cnt, 1u, __ATOMIC_RELEASE,
                                          __HIP_MEMORY_SCOPE_AGENT);
    if (old == (unsigned)(NB - 1)) {
      __hip_atomic_store(flg, 1u, __ATOMIC_RELEASE, __HIP_MEMORY_SCOPE_AGENT);
    } else {
      while (__hip_atomic_load(flg, __ATOMIC_RELAXED,
                               __HIP_MEMORY_SCOPE_AGENT) == 0u)
        __builtin_amdgcn_s_sleep(4);   // ~256-cycle poll granularity
    }
  }
  __syncthreads();
  __threadfence();                     // acquire: invalidate stale caches before reads
}

// One l-row contribution (quad scheme: 4 lanes own one 32-float row, 8 floats each).
__device__ __forceinline__ void trip_body(const v8f (&A)[4], v8f zv,
                                          const float* sRel, bool dorel, int relrow,
                                          v8f (&S)[4], v4f& Zc) {
  float d0 = 0.f, d1 = 0.f, d2 = 0.f, d3 = 0.f;
  #pragma unroll
  for (int k = 0; k < 8; ++k) {
    d0 = fmaf(A[0][k], zv[k], d0);
    d1 = fmaf(A[1][k], zv[k], d1);
    d2 = fmaf(A[2][k], zv[k], d2);
    d3 = fmaf(A[3][k], zv[k], d3);
  }
  d0 += __shfl_xor(d0, 1); d0 += __shfl_xor(d0, 2);
  d1 += __shfl_xor(d1, 1); d1 += __shfl_xor(d1, 2);
  d2 += __shfl_xor(d2, 1); d2 += __shfl_xor(d2, 2);
  d3 += __shfl_xor(d3, 1); d3 += __shfl_xor(d3, 2);
  if (dorel) {
    const float4 r = reinterpret_cast<const float4*>(sRel)[relrow];
    d0 += r.x; d1 += r.y; d2 += r.z; d3 += r.w;
  }
  float w0 = __expf(d0), w1 = __expf(d1), w2 = __expf(d2), w3 = __expf(d3);
  Zc[0] += w0; Zc[1] += w1; Zc[2] += w2; Zc[3] += w3;
  S[0] += zv * w0;
  S[1] += zv * w1;
  S[2] += zv * w2;
  S[3] += zv * w3;
}

__global__ __launch_bounds__(BT)
void photonic_kernel(PParams p) {
  __shared__ float sZ[32];
  __shared__ float sQ[32];
  __shared__ float sOutV[32];
  __shared__ float sZn[32];
  __shared__ __align__(16) float sA[128];     // a[h][c]
  __shared__ __align__(16) float sRel[256];   // relT[l][h], l<64
  __shared__ float sRed[BT / 64][4][36];      // per-wave reduced (S[4][8] + Z[4]) per quarter
  __shared__ float sP[132][4];                // level-2 strip sums
  __shared__ float sSS[128];                  // global-reduced S[h][c]
  __shared__ float sSZ[4];                    // global-reduced Z[h]
  __shared__ __align__(16) float sZp[LDSR * 32];  // LDS-resident z rows (dense 128 B)

  const int tid  = threadIdx.x;
  const int b    = blockIdx.x;
  const int j    = tid & 3;        // quarter (owns columns [8j, 8j+8))
  const int quad = tid >> 2;       // 0..127
  const int wave = tid >> 6;
  const int lane = tid & 63;

  const int chunk0 = b * CHUNK;
  const int clen   = min(CHUNK, p.L - chunk0);   // 1954, last block 1730
  const int ldsl   = min(clen, (int)LDSR);       // 1120 everywhere

  // init state z = candidate (real-interleaved flat 32)
  if (tid < 32) sZ[tid] = p.candidate[tid];
  __syncthreads();
  compute_qar(p, tid, sZ, sQ, sA, sRel);

  for (int iter = 0; iter < MSTEPS; ++iter) {
    // stage my quarter of a[h][*] into registers
    v8f A[4];
    #pragma unroll
    for (int h = 0; h < 4; ++h)
      A[h] = *reinterpret_cast<const v8f*>(sA + h * 32 + j * 8);

    v8f S[4];
    #pragma unroll
    for (int h = 0; h < 4; ++h) S[h] = 0.f;
    v4f Zc = 0.f;

    if (iter == 0) {
      // ---- first pass: LDS rows come from HBM and are stashed; rest streamed ----
      #pragma unroll
      for (int t = 0; t < 9; ++t) {
        int li = quad + (t << 7);
        if (li < ldsl) {
          v8f zv = *reinterpret_cast<const v8f*>(
              p.z_past + (size_t)(chunk0 + li) * 32 + j * 8);
          float* dst = sZp + li * 32 + j * 8;
          *reinterpret_cast<v4f*>(dst)     = __builtin_shufflevector(zv, zv, 0, 1, 2, 3);
          *reinterpret_cast<v4f*>(dst + 4) = __builtin_shufflevector(zv, zv, 4, 5, 6, 7);
          trip_body(A, zv, sRel, (b == 0) && (t == 0) && (quad < 64), quad, S, Zc);
        }
      }
    } else {
      // ---- steady state: LDS-resident rows ----
      #pragma unroll
      for (int t = 0; t < 9; ++t) {
        int li = quad + (t << 7);
        if (li < ldsl) {
          const float* src = sZp + li * 32 + j * 8;
          v4f a4 = *reinterpret_cast<const v4f*>(src);
          v4f b4 = *reinterpret_cast<const v4f*>(src + 4);
          v8f zv = __builtin_shufflevector(a4, b4, 0, 1, 2, 3, 4, 5, 6, 7);
          trip_body(A, zv, sRel, (b == 0) && (t == 0) && (quad < 64), quad, S, Zc);
        }
      }
    }
    // ---- streamed remainder (27 MB grid-wide; L3-resident after pass 1) ----
    for (int r = LDSR + quad; r < clen; r += 128) {
      v8f zv = *reinterpret_cast<const v8f*>(
          p.z_past + (size_t)(chunk0 + r) * 32 + j * 8);
      trip_body(A, zv, sRel, false, 0, S, Zc);
    }

    // reduce across the 16 quads of each wave (lane%4 == quarter is preserved)
    #pragma unroll
    for (int m = 4; m <= 32; m <<= 1) {
      #pragma unroll
      for (int h = 0; h < 4; ++h) {
        #pragma unroll
        for (int k = 0; k < 8; ++k) S[h][k] += __shfl_xor(S[h][k], m);
        Zc[h] += __shfl_xor(Zc[h], m);
      }
    }
    if ((lane >> 2) == 0) {  // lanes 0..3: lane == quarter j
      #pragma unroll
      for (int h = 0; h < 4; ++h) {
        #pragma unroll
        for (int k = 0; k < 8; ++k) sRed[wave][lane][h * 8 + k] = S[h][k];
        sRed[wave][lane][32 + h] = Zc[h];
      }
    }
    __syncthreads();

    // per-block partials -> global, component-major [comp][block] for coalesced reduce
    float* part = p.ws + 16 + (iter & 1) * (132 * NB);
    if (tid < 132) {
      float acc = 0.f;
      if (tid < 128) {
        int h = tid >> 5, c = tid & 31;
        int jj = c >> 3, k = c & 7;
        #pragma unroll
        for (int w2 = 0; w2 < BT / 64; ++w2) acc += sRed[w2][jj][h * 8 + k];
        part[(h * 33 + c) * NB + b] = acc;
      } else {
        int h = tid - 128;
        #pragma unroll
        for (int w2 = 0; w2 < BT / 64; ++w2) acc += sRed[w2][0][32 + h];
        part[(h * 33 + 32) * NB + b] = acc;
      }
    }

    grid_barrier(p.ws, iter, tid);

    // level-2 reduce, ALL 512 threads: thread t sums a 16-float4 strip of one
    // component row (132 rows x 256 floats). Independent loads -> one latency burst.
    {
      const int cc = tid >> 2;       // component 0..127
      const int qq = tid & 3;        // quarter-strip within the 256-wide row
      const float4* pp =
          reinterpret_cast<const float4*>(part + cc * NB) + qq * (NB / 16);
      float acc = 0.f;
      #pragma unroll
      for (int i = 0; i < NB / 16; ++i) {
        float4 v4 = pp[i];
        acc += (v4.x + v4.y) + (v4.z + v4.w);
      }
      sP[cc][qq] = acc;
      if (tid < 16) {                // components 128..131 (the Z row)
        const int cc2 = 128 + (tid >> 2);
        const float4* pp2 =
            reinterpret_cast<const float4*>(part + cc2 * NB) + qq * (NB / 16);
        float acc2 = 0.f;
        #pragma unroll
        for (int i = 0; i < NB / 16; ++i) {
          float4 v4 = pp2[i];
          acc2 += (v4.x + v4.y) + (v4.z + v4.w);
        }
        sP[cc2][qq] = acc2;
      }
    }
    __syncthreads();
    if (tid < 132) {
      float acc = sP[tid][0] + sP[tid][1] + sP[tid][2] + sP[tid][3];
      int h = tid / 33, k = tid % 33;
      if (k < 32) sSS[h * 32 + k] = acc; else sSZ[h] = acc;
    }
    __syncthreads();

    // out_flat[j'] = v_w[j',:] @ (S_h / Z_h) + v_b[j']   (h = j'>>3)
    if (tid < 32) {
      int h = tid >> 3;
      float acc = 0.f;
      const float* row = p.v_w + tid * 32;
      #pragma unroll
      for (int c = 0; c < 32; ++c) acc = fmaf(row[c], sSS[h * 32 + c], acc);
      sOutV[tid] = acc / sSZ[h] + p.v_b[tid];
    }
    __syncthreads();
    // mod = o_w @ out + o_b ; z += coupling*mod ; mish
    if (tid < 32) {
      float acc = p.o_b[tid];
      const float* row = p.o_w + tid * 32;
      #pragma unroll
      for (int c = 0; c < 32; ++c) acc = fmaf(row[c], sOutV[c], acc);
      float zv2 = sZ[tid] + p.coupling[0] * acc;
      sZn[tid] = mish_f(zv2);
    }
    __syncthreads();
    // layer-norm over the 16 real / 16 imag components separately
    if (tid < 32) {
      int par = tid & 1;
      float m = 0.f;
      #pragma unroll
      for (int e = 0; e < 16; ++e) m += sZn[2 * e + par];
      m *= (1.f / 16.f);
      float v = 0.f;
      #pragma unroll
      for (int e = 0; e < 16; ++e) { float dd = sZn[2 * e + par] - m; v = fmaf(dd, dd, v); }
      v *= (1.f / 16.f);
      sZ[tid] = (sZn[tid] - m) * rsqrtf(v + 1e-5f) * p.norm_scale[0];
    }
    __syncthreads();

    if (iter != MSTEPS - 1) {
      compute_qar(p, tid, sZ, sQ, sA, sRel);
    } else {
      if (b == 0 && tid < 32) p.out[tid] = sZ[tid];
    }
  }
}

extern "C" void kernel_launch(void* const* d_in, const int* in_sizes, int n_in,
                              void* d_out, int out_size, void* d_ws, size_t ws_size,
                              hipStream_t stream) {
  PParams p;
  p.candidate  = (const float*)d_in[0];
  p.z_past     = (const float*)d_in[1];
  p.q_w = (const float*)d_in[2];  p.q_b = (const float*)d_in[3];
  p.k_w = (const float*)d_in[4];  p.k_b = (const float*)d_in[5];
  p.v_w = (const float*)d_in[6];  p.v_b = (const float*)d_in[7];
  p.o_w = (const float*)d_in[8];  p.o_b = (const float*)d_in[9];
  p.rel_bias   = (const float*)d_in[10];
  p.coupling   = (const float*)d_in[11];
  p.norm_scale = (const float*)d_in[12];
  p.out = (float*)d_out;
  p.ws  = (float*)d_ws;
  p.L   = in_sizes[1] / 32;

  // zero the 16 barrier words (captured as a graph node -> re-zeroed every replay)
  hipMemsetAsync(d_ws, 0, 64, stream);

  void* args[] = { &p };
  hipLaunchCooperativeKernel((const void*)photonic_kernel,
                             dim3(NB), dim3(BT), args, 0, stream);
}

// Round 7
// 538.511 us; speedup vs baseline: 2.6013x; 1.5322x over previous
//
#include <hip/hip_runtime.h>
#include <hip/hip_cooperative_groups.h>

namespace cg = cooperative_groups;

#define NB 256            // blocks (1 per CU)
#define BT 512            // threads per block (8 waves) — the no-spill config
#define MSTEPS 8
// Fixed problem shape: L = 500000.
#define CHUNK 1954        // ceil(500000 / NB) rows per block
#define LDSR 1120         // rows resident in LDS (dense 128 B rows, 143 KB)

typedef float v8f __attribute__((ext_vector_type(8)));
typedef float v4f __attribute__((ext_vector_type(4)));

struct PParams {
  const float* candidate;
  const float* z_past;
  const float* q_w; const float* q_b;
  const float* k_w; const float* k_b;
  const float* v_w; const float* v_b;
  const float* o_w; const float* o_b;
  const float* rel_bias;
  const float* coupling;
  const float* norm_scale;
  float* out;
  float* ws;   // [0..15] reserved; [16..] 2*132*NB partials (double-buffered)
  int L;
};

__device__ __forceinline__ float mish_f(float x) {
  float sp = fmaxf(x, 0.0f) + log1pf(expf(-fabsf(x)));
  return x * tanhf(sp);
}

// Recompute q projection, folded score vectors a_h (pre-scaled by inv_sqrt_d=0.5),
// and the l<64 relative-bias delta table, from the current state sZ.
// Must be called by ALL threads of the block (contains barriers).
__device__ void compute_qar(const PParams& p, int tid,
                            float* sZ, float* sQ, float* sA, float* sRel) {
  if (tid < 32) {
    float acc = p.q_b[tid];
    const float* row = p.q_w + tid * 32;
    #pragma unroll
    for (int c = 0; c < 32; ++c) acc = fmaf(row[c], sZ[c], acc);
    sQ[tid] = acc;
  }
  __syncthreads();
  if (tid < 128) {
    int h = tid >> 5, c = tid & 31;
    float acc = 0.f;
    #pragma unroll
    for (int jj = 0; jj < 8; ++jj)
      acc = fmaf(sQ[8 * h + jj], p.k_w[(8 * h + jj) * 32 + c], acc);
    sA[tid] = 0.5f * acc;               // fold inv_sqrt_d
  }
  if (tid >= 256) {
    // rel-bias delta vs the saturated idx=128 entry (constant part cancels in softmax)
    int t = tid - 256;
    int l = t >> 2, h = t & 3;
    float acc = 0.f;
    #pragma unroll
    for (int jj = 0; jj < 8; ++jj) {
      int jidx = 8 * h + jj;
      acc = fmaf(sQ[jidx],
                 p.rel_bias[(l + 64) * 32 + jidx] - p.rel_bias[128 * 32 + jidx],
                 acc);
    }
    sRel[t] = 0.5f * acc;
  }
  __syncthreads();
}

// One l-row contribution (quad scheme: 4 lanes own one 32-float row, 8 floats each).
__device__ __forceinline__ void trip_body(const v8f (&A)[4], v8f zv,
                                          const float* sRel, bool dorel, int relrow,
                                          v8f (&S)[4], v4f& Zc) {
  float d0 = 0.f, d1 = 0.f, d2 = 0.f, d3 = 0.f;
  #pragma unroll
  for (int k = 0; k < 8; ++k) {
    d0 = fmaf(A[0][k], zv[k], d0);
    d1 = fmaf(A[1][k], zv[k], d1);
    d2 = fmaf(A[2][k], zv[k], d2);
    d3 = fmaf(A[3][k], zv[k], d3);
  }
  d0 += __shfl_xor(d0, 1); d0 += __shfl_xor(d0, 2);
  d1 += __shfl_xor(d1, 1); d1 += __shfl_xor(d1, 2);
  d2 += __shfl_xor(d2, 1); d2 += __shfl_xor(d2, 2);
  d3 += __shfl_xor(d3, 1); d3 += __shfl_xor(d3, 2);
  if (dorel) {
    const float4 r = reinterpret_cast<const float4*>(sRel)[relrow];
    d0 += r.x; d1 += r.y; d2 += r.z; d3 += r.w;
  }
  float w0 = __expf(d0), w1 = __expf(d1), w2 = __expf(d2), w3 = __expf(d3);
  Zc[0] += w0; Zc[1] += w1; Zc[2] += w2; Zc[3] += w3;
  S[0] += zv * w0;
  S[1] += zv * w1;
  S[2] += zv * w2;
  S[3] += zv * w3;
}

__global__ __launch_bounds__(BT)
void photonic_kernel(PParams p) {
  cg::grid_group grid = cg::this_grid();

  __shared__ float sZ[32];
  __shared__ float sQ[32];
  __shared__ float sOutV[32];
  __shared__ float sZn[32];
  __shared__ __align__(16) float sA[128];     // a[h][c]
  __shared__ __align__(16) float sRel[256];   // relT[l][h], l<64
  __shared__ float sRed[BT / 64][4][36];      // per-wave reduced (S[4][8] + Z[4]) per quarter
  __shared__ float sP[132][4];                // level-2 strip sums
  __shared__ float sSS[128];                  // global-reduced S[h][c]
  __shared__ float sSZ[4];                    // global-reduced Z[h]
  __shared__ __align__(16) float sZp[LDSR * 32];  // LDS-resident z rows (dense 128 B)

  const int tid  = threadIdx.x;
  const int b    = blockIdx.x;
  const int j    = tid & 3;        // quarter (owns columns [8j, 8j+8))
  const int quad = tid >> 2;       // 0..127
  const int wave = tid >> 6;
  const int lane = tid & 63;

  const int chunk0 = b * CHUNK;
  const int clen   = min(CHUNK, p.L - chunk0);   // 1954, last block 1730
  const int ldsl   = min(clen, (int)LDSR);       // 1120 everywhere

  // init state z = candidate (real-interleaved flat 32)
  if (tid < 32) sZ[tid] = p.candidate[tid];
  __syncthreads();
  compute_qar(p, tid, sZ, sQ, sA, sRel);

  for (int iter = 0; iter < MSTEPS; ++iter) {
    // stage my quarter of a[h][*] into registers
    v8f A[4];
    #pragma unroll
    for (int h = 0; h < 4; ++h)
      A[h] = *reinterpret_cast<const v8f*>(sA + h * 32 + j * 8);

    v8f S[4];
    #pragma unroll
    for (int h = 0; h < 4; ++h) S[h] = 0.f;
    v4f Zc = 0.f;

    if (iter == 0) {
      // ---- first pass: LDS rows come from HBM and are stashed; rest streamed ----
      #pragma unroll
      for (int t = 0; t < 9; ++t) {
        int li = quad + (t << 7);
        if (li < ldsl) {
          v8f zv = *reinterpret_cast<const v8f*>(
              p.z_past + (size_t)(chunk0 + li) * 32 + j * 8);
          float* dst = sZp + li * 32 + j * 8;
          *reinterpret_cast<v4f*>(dst)     = __builtin_shufflevector(zv, zv, 0, 1, 2, 3);
          *reinterpret_cast<v4f*>(dst + 4) = __builtin_shufflevector(zv, zv, 4, 5, 6, 7);
          trip_body(A, zv, sRel, (b == 0) && (t == 0) && (quad < 64), quad, S, Zc);
        }
      }
    } else {
      // ---- steady state: LDS-resident rows ----
      #pragma unroll
      for (int t = 0; t < 9; ++t) {
        int li = quad + (t << 7);
        if (li < ldsl) {
          const float* src = sZp + li * 32 + j * 8;
          v4f a4 = *reinterpret_cast<const v4f*>(src);
          v4f b4 = *reinterpret_cast<const v4f*>(src + 4);
          v8f zv = __builtin_shufflevector(a4, b4, 0, 1, 2, 3, 4, 5, 6, 7);
          trip_body(A, zv, sRel, (b == 0) && (t == 0) && (quad < 64), quad, S, Zc);
        }
      }
    }
    // ---- streamed remainder (27 MB grid-wide; L3-resident after pass 1) ----
    for (int r = LDSR + quad; r < clen; r += 128) {
      v8f zv = *reinterpret_cast<const v8f*>(
          p.z_past + (size_t)(chunk0 + r) * 32 + j * 8);
      trip_body(A, zv, sRel, false, 0, S, Zc);
    }

    // reduce across the 16 quads of each wave (lane%4 == quarter is preserved)
    #pragma unroll
    for (int m = 4; m <= 32; m <<= 1) {
      #pragma unroll
      for (int h = 0; h < 4; ++h) {
        #pragma unroll
        for (int k = 0; k < 8; ++k) S[h][k] += __shfl_xor(S[h][k], m);
        Zc[h] += __shfl_xor(Zc[h], m);
      }
    }
    if ((lane >> 2) == 0) {  // lanes 0..3: lane == quarter j
      #pragma unroll
      for (int h = 0; h < 4; ++h) {
        #pragma unroll
        for (int k = 0; k < 8; ++k) sRed[wave][lane][h * 8 + k] = S[h][k];
        sRed[wave][lane][32 + h] = Zc[h];
      }
    }
    __syncthreads();

    // per-block partials -> global, component-major [comp][block] for coalesced reduce
    float* part = p.ws + 16 + (iter & 1) * (132 * NB);
    if (tid < 132) {
      float acc = 0.f;
      if (tid < 128) {
        int h = tid >> 5, c = tid & 31;
        int jj = c >> 3, k = c & 7;
        #pragma unroll
        for (int w2 = 0; w2 < BT / 64; ++w2) acc += sRed[w2][jj][h * 8 + k];
        part[(h * 33 + c) * NB + b] = acc;
      } else {
        int h = tid - 128;
        #pragma unroll
        for (int w2 = 0; w2 < BT / 64; ++w2) acc += sRed[w2][0][32 + h];
        part[(h * 33 + 32) * NB + b] = acc;
      }
    }

    grid.sync();   // proven ~10-15 µs/iter in round 0 (vs ~70+ for the hand-rolled barrier)

    // level-2 reduce, ALL 512 threads: thread t sums a 16-float4 strip of one
    // component row (132 rows x 256 floats). Independent loads -> one latency burst.
    {
      const int cc = tid >> 2;       // component 0..127
      const int qq = tid & 3;        // quarter-strip within the 256-wide row
      const float4* pp =
          reinterpret_cast<const float4*>(part + cc * NB) + qq * (NB / 16);
      float acc = 0.f;
      #pragma unroll
      for (int i = 0; i < NB / 16; ++i) {
        float4 v4 = pp[i];
        acc += (v4.x + v4.y) + (v4.z + v4.w);
      }
      sP[cc][qq] = acc;
      if (tid < 16) {                // components 128..131 (the Z row)
        const int cc2 = 128 + (tid >> 2);
        const float4* pp2 =
            reinterpret_cast<const float4*>(part + cc2 * NB) + qq * (NB / 16);
        float acc2 = 0.f;
        #pragma unroll
        for (int i = 0; i < NB / 16; ++i) {
          float4 v4 = pp2[i];
          acc2 += (v4.x + v4.y) + (v4.z + v4.w);
        }
        sP[cc2][qq] = acc2;
      }
    }
    __syncthreads();
    if (tid < 132) {
      float acc = sP[tid][0] + sP[tid][1] + sP[tid][2] + sP[tid][3];
      int h = tid / 33, k = tid % 33;
      if (k < 32) sSS[h * 32 + k] = acc; else sSZ[h] = acc;
    }
    __syncthreads();

    // out_flat[j'] = v_w[j',:] @ (S_h / Z_h) + v_b[j']   (h = j'>>3)
    if (tid < 32) {
      int h = tid >> 3;
      float acc = 0.f;
      const float* row = p.v_w + tid * 32;
      #pragma unroll
      for (int c = 0; c < 32; ++c) acc = fmaf(row[c], sSS[h * 32 + c], acc);
      sOutV[tid] = acc / sSZ[h] + p.v_b[tid];
    }
    __syncthreads();
    // mod = o_w @ out + o_b ; z += coupling*mod ; mish
    if (tid < 32) {
      float acc = p.o_b[tid];
      const float* row = p.o_w + tid * 32;
      #pragma unroll
      for (int c = 0; c < 32; ++c) acc = fmaf(row[c], sOutV[c], acc);
      float zv2 = sZ[tid] + p.coupling[0] * acc;
      sZn[tid] = mish_f(zv2);
    }
    __syncthreads();
    // layer-norm over the 16 real / 16 imag components separately
    if (tid < 32) {
      int par = tid & 1;
      float m = 0.f;
      #pragma unroll
      for (int e = 0; e < 16; ++e) m += sZn[2 * e + par];
      m *= (1.f / 16.f);
      float v = 0.f;
      #pragma unroll
      for (int e = 0; e < 16; ++e) { float dd = sZn[2 * e + par] - m; v = fmaf(dd, dd, v); }
      v *= (1.f / 16.f);
      sZ[tid] = (sZn[tid] - m) * rsqrtf(v + 1e-5f) * p.norm_scale[0];
    }
    __syncthreads();

    if (iter != MSTEPS - 1) {
      compute_qar(p, tid, sZ, sQ, sA, sRel);
    } else {
      if (b == 0 && tid < 32) p.out[tid] = sZ[tid];
    }
  }
}

extern "C" void kernel_launch(void* const* d_in, const int* in_sizes, int n_in,
                              void* d_out, int out_size, void* d_ws, size_t ws_size,
                              hipStream_t stream) {
  PParams p;
  p.candidate  = (const float*)d_in[0];
  p.z_past     = (const float*)d_in[1];
  p.q_w = (const float*)d_in[2];  p.q_b = (const float*)d_in[3];
  p.k_w = (const float*)d_in[4];  p.k_b = (const float*)d_in[5];
  p.v_w = (const float*)d_in[6];  p.v_b = (const float*)d_in[7];
  p.o_w = (const float*)d_in[8];  p.o_b = (const float*)d_in[9];
  p.rel_bias   = (const float*)d_in[10];
  p.coupling   = (const float*)d_in[11];
  p.norm_scale = (const float*)d_in[12];
  p.out = (float*)d_out;
  p.ws  = (float*)d_ws;
  p.L   = in_sizes[1] / 32;

  void* args[] = { &p };
  hipLaunchCooperativeKernel((const void*)photonic_kernel,
                             dim3(NB), dim3(BT), args, 0, stream);
}

// Round 9
// 321.732 us; speedup vs baseline: 4.3540x; 1.6738x over previous
//
#include <hip/hip_runtime.h>

#define NB 256            // blocks (1 per CU)
#define BT 512            // threads per block (8 waves) — the no-spill config
#define MSTEPS 8
// Fixed problem shape: L = 500000.
#define CHUNK 1954        // ceil(500000 / NB) rows per block
#define LDSR 1120         // rows resident in LDS (dense 128 B rows, 143 KB)

typedef float v8f __attribute__((ext_vector_type(8)));
typedef float v4f __attribute__((ext_vector_type(4)));

// Workspace layout:
//  u32 region (memset to 0 at launch, 5120 B):
//    per-iter counter block, stride 160 u32 (10 separate 64 B lines):
//      [iter*160 + g*16] : sub-arrival counter, block-group g = b>>5 (8 groups of 32)
//      [iter*160 + 128]  : super-arrival counter
//      [iter*160 + 144]  : release flag
//  float region at ws + 1280:
//    per-iteration partial tables, 132*NB floats each, NO reuse within a launch.
//    Stores to them are system-scope (performed at the coherent point, bypassing
//    L1/L2); reads are plain cached loads — safe because each buffer's lines are
//    first touched only AFTER that iter's flag, and caches are invalidated at
//    kernel dispatch, so no stale copy can exist (r8 failure mode closed).

struct PParams {
  const float* candidate;
  const float* z_past;
  const float* q_w; const float* q_b;
  const float* k_w; const float* k_b;
  const float* v_w; const float* v_b;
  const float* o_w; const float* o_b;
  const float* rel_bias;
  const float* coupling;
  const float* norm_scale;
  float* out;
  float* ws;
  int L;
};

__device__ __forceinline__ float mish_f(float x) {
  float sp = fmaxf(x, 0.0f) + log1pf(expf(-fabsf(x)));
  return x * tanhf(sp);
}

// Recompute q projection, folded score vectors a_h (pre-scaled by inv_sqrt_d=0.5),
// and the l<64 relative-bias delta table, from the current state sZ.
// Must be called by ALL threads of the block (contains barriers).
__device__ void compute_qar(const PParams& p, int tid,
                            float* sZ, float* sQ, float* sA, float* sRel) {
  if (tid < 32) {
    float acc = p.q_b[tid];
    const float* row = p.q_w + tid * 32;
    #pragma unroll
    for (int c = 0; c < 32; ++c) acc = fmaf(row[c], sZ[c], acc);
    sQ[tid] = acc;
  }
  __syncthreads();
  if (tid < 128) {
    int h = tid >> 5, c = tid & 31;
    float acc = 0.f;
    #pragma unroll
    for (int jj = 0; jj < 8; ++jj)
      acc = fmaf(sQ[8 * h + jj], p.k_w[(8 * h + jj) * 32 + c], acc);
    sA[tid] = 0.5f * acc;               // fold inv_sqrt_d
  }
  if (tid >= 256) {
    // rel-bias delta vs the saturated idx=128 entry (constant part cancels in softmax)
    int t = tid - 256;
    int l = t >> 2, h = t & 3;
    float acc = 0.f;
    #pragma unroll
    for (int jj = 0; jj < 8; ++jj) {
      int jidx = 8 * h + jj;
      acc = fmaf(sQ[jidx],
                 p.rel_bias[(l + 64) * 32 + jidx] - p.rel_bias[128 * 32 + jidx],
                 acc);
    }
    sRel[t] = 0.5f * acc;
  }
  __syncthreads();
}

// One l-row contribution (quad scheme: 4 lanes own one 32-float row, 8 floats each).
__device__ __forceinline__ void trip_body(const v8f (&A)[4], v8f zv,
                                          const float* sRel, bool dorel, int relrow,
                                          v8f (&S)[4], v4f& Zc) {
  float d0 = 0.f, d1 = 0.f, d2 = 0.f, d3 = 0.f;
  #pragma unroll
  for (int k = 0; k < 8; ++k) {
    d0 = fmaf(A[0][k], zv[k], d0);
    d1 = fmaf(A[1][k], zv[k], d1);
    d2 = fmaf(A[2][k], zv[k], d2);
    d3 = fmaf(A[3][k], zv[k], d3);
  }
  d0 += __shfl_xor(d0, 1); d0 += __shfl_xor(d0, 2);
  d1 += __shfl_xor(d1, 1); d1 += __shfl_xor(d1, 2);
  d2 += __shfl_xor(d2, 1); d2 += __shfl_xor(d2, 2);
  d3 += __shfl_xor(d3, 1); d3 += __shfl_xor(d3, 2);
  if (dorel) {
    const float4 r = reinterpret_cast<const float4*>(sRel)[relrow];
    d0 += r.x; d1 += r.y; d2 += r.z; d3 += r.w;
  }
  float w0 = __expf(d0), w1 = __expf(d1), w2 = __expf(d2), w3 = __expf(d3);
  Zc[0] += w0; Zc[1] += w1; Zc[2] += w2; Zc[3] += w3;
  S[0] += zv * w0;
  S[1] += zv * w1;
  S[2] += zv * w2;
  S[3] += zv * w3;
}

__global__ __launch_bounds__(BT)
void photonic_kernel(PParams p) {
  __shared__ float sZ[32];
  __shared__ float sQ[32];
  __shared__ float sOutV[32];
  __shared__ float sZn[32];
  __shared__ __align__(16) float sA[128];     // a[h][c]
  __shared__ __align__(16) float sRel[256];   // relT[l][h], l<64
  __shared__ float sRed[BT / 64][4][36];      // per-wave reduced (S[4][8] + Z[4]) per quarter
  __shared__ float sP[132][4];                // level-2 strip sums
  __shared__ float sSS[128];                  // global-reduced S[h][c]
  __shared__ float sSZ[4];                    // global-reduced Z[h]
  __shared__ __align__(16) float sZp[LDSR * 32];  // LDS-resident z rows (dense 128 B)

  const int tid  = threadIdx.x;
  const int b    = blockIdx.x;
  const int j    = tid & 3;        // quarter (owns columns [8j, 8j+8))
  const int quad = tid >> 2;       // 0..127
  const int wave = tid >> 6;
  const int lane = tid & 63;

  const int chunk0 = b * CHUNK;
  const int clen   = min(CHUNK, p.L - chunk0);   // 1954, last block 1730
  const int ldsl   = min(clen, (int)LDSR);       // 1120 everywhere

  // init state z = candidate (real-interleaved flat 32)
  if (tid < 32) sZ[tid] = p.candidate[tid];
  __syncthreads();
  compute_qar(p, tid, sZ, sQ, sA, sRel);

  for (int iter = 0; iter < MSTEPS; ++iter) {
    // stage my quarter of a[h][*] into registers
    v8f A[4];
    #pragma unroll
    for (int h = 0; h < 4; ++h)
      A[h] = *reinterpret_cast<const v8f*>(sA + h * 32 + j * 8);

    v8f S[4];
    #pragma unroll
    for (int h = 0; h < 4; ++h) S[h] = 0.f;
    v4f Zc = 0.f;

    if (iter == 0) {
      // ---- first pass: LDS rows come from HBM and are stashed; rest streamed ----
      #pragma unroll
      for (int t = 0; t < 9; ++t) {
        int li = quad + (t << 7);
        if (li < ldsl) {
          v8f zv = *reinterpret_cast<const v8f*>(
              p.z_past + (size_t)(chunk0 + li) * 32 + j * 8);
          float* dst = sZp + li * 32 + j * 8;
          *reinterpret_cast<v4f*>(dst)     = __builtin_shufflevector(zv, zv, 0, 1, 2, 3);
          *reinterpret_cast<v4f*>(dst + 4) = __builtin_shufflevector(zv, zv, 4, 5, 6, 7);
          trip_body(A, zv, sRel, (b == 0) && (t == 0) && (quad < 64), quad, S, Zc);
        }
      }
    } else {
      // ---- steady state: LDS-resident rows ----
      #pragma unroll
      for (int t = 0; t < 9; ++t) {
        int li = quad + (t << 7);
        if (li < ldsl) {
          const float* src = sZp + li * 32 + j * 8;
          v4f a4 = *reinterpret_cast<const v4f*>(src);
          v4f b4 = *reinterpret_cast<const v4f*>(src + 4);
          v8f zv = __builtin_shufflevector(a4, b4, 0, 1, 2, 3, 4, 5, 6, 7);
          trip_body(A, zv, sRel, (b == 0) && (t == 0) && (quad < 64), quad, S, Zc);
        }
      }
    }
    // ---- streamed remainder (27 MB grid-wide; L2/L3-resident after pass 1 —
    //      no cache-invalidating fences anywhere in this design) ----
    for (int r = LDSR + quad; r < clen; r += 128) {
      v8f zv = *reinterpret_cast<const v8f*>(
          p.z_past + (size_t)(chunk0 + r) * 32 + j * 8);
      trip_body(A, zv, sRel, false, 0, S, Zc);
    }

    // reduce across the 16 quads of each wave (lane%4 == quarter is preserved)
    #pragma unroll
    for (int m = 4; m <= 32; m <<= 1) {
      #pragma unroll
      for (int h = 0; h < 4; ++h) {
        #pragma unroll
        for (int k = 0; k < 8; ++k) S[h][k] += __shfl_xor(S[h][k], m);
        Zc[h] += __shfl_xor(Zc[h], m);
      }
    }
    if ((lane >> 2) == 0) {  // lanes 0..3: lane == quarter j
      #pragma unroll
      for (int h = 0; h < 4; ++h) {
        #pragma unroll
        for (int k = 0; k < 8; ++k) sRed[wave][lane][h * 8 + k] = S[h][k];
        sRed[wave][lane][32 + h] = Zc[h];
      }
    }
    __syncthreads();

    // ---- publish per-block partials with system-scope stores (performed at the
    //      coherent point; deterministic — same summation order as before) ----
    float* pb = p.ws + 1280 + iter * (132 * NB);
    if (tid < 132) {
      float acc = 0.f;
      if (tid < 128) {
        int h = tid >> 5, c = tid & 31;
        int jj = c >> 3, k = c & 7;
        #pragma unroll
        for (int w2 = 0; w2 < BT / 64; ++w2) acc += sRed[w2][jj][h * 8 + k];
      } else {
        int h = tid - 128;
        #pragma unroll
        for (int w2 = 0; w2 < BT / 64; ++w2) acc += sRed[w2][0][32 + h];
      }
      __hip_atomic_store(&pb[tid * NB + b], acc, __ATOMIC_RELAXED,
                         __HIP_MEMORY_SCOPE_SYSTEM);
    }
    // every wave drains its own stores, then the block barrier guarantees all
    // 132 stores of this block are performed before tid 0 arrives.
    asm volatile("s_waitcnt vmcnt(0)" ::: "memory");
    __syncthreads();

    // ---- two-level arrival + flag barrier, all at the coherent point ----
    {
      unsigned* cbase = reinterpret_cast<unsigned*>(p.ws) + iter * 160;
      if (tid == 0) {
        unsigned* sub = cbase + ((b >> 5) << 4);   // 8 counters, separate lines
        unsigned* sup = cbase + 128;
        unsigned* flg = cbase + 144;
        if (__hip_atomic_fetch_add(sub, 1u, __ATOMIC_RELAXED,
                                   __HIP_MEMORY_SCOPE_SYSTEM) == 31u) {
          if (__hip_atomic_fetch_add(sup, 1u, __ATOMIC_RELAXED,
                                     __HIP_MEMORY_SCOPE_SYSTEM) == 7u) {
            __hip_atomic_store(flg, 1u, __ATOMIC_RELAXED,
                               __HIP_MEMORY_SCOPE_SYSTEM);
          }
        }
        while (__hip_atomic_load(flg, __ATOMIC_RELAXED,
                                 __HIP_MEMORY_SCOPE_SYSTEM) == 0u)
          __builtin_amdgcn_s_sleep(1);
      }
      __syncthreads();
    }

    // ---- level-2 reduce with plain coalesced float4 loads (fresh per-iter
    //      buffer: no stale cache copies possible). ALL 512 threads. ----
    {
      const int cc = tid >> 2;       // component 0..127
      const int qq = tid & 3;        // quarter-strip within the 256-wide row
      const float4* pp =
          reinterpret_cast<const float4*>(pb + cc * NB) + qq * (NB / 16);
      float acc = 0.f;
      #pragma unroll
      for (int i = 0; i < NB / 16; ++i) {
        float4 v4 = pp[i];
        acc += (v4.x + v4.y) + (v4.z + v4.w);
      }
      sP[cc][qq] = acc;
      if (tid < 16) {                // components 128..131 (the Z row)
        const int cc2 = 128 + (tid >> 2);
        const float4* pp2 =
            reinterpret_cast<const float4*>(pb + cc2 * NB) + qq * (NB / 16);
        float acc2 = 0.f;
        #pragma unroll
        for (int i = 0; i < NB / 16; ++i) {
          float4 v4 = pp2[i];
          acc2 += (v4.x + v4.y) + (v4.z + v4.w);
        }
        sP[cc2][qq] = acc2;
      }
    }
    __syncthreads();
    if (tid < 132) {
      float acc = sP[tid][0] + sP[tid][1] + sP[tid][2] + sP[tid][3];
      if (tid < 128) sSS[tid] = acc; else sSZ[tid - 128] = acc;
    }
    __syncthreads();

    // out_flat[j'] = v_w[j',:] @ (S_h / Z_h) + v_b[j']   (h = j'>>3)
    if (tid < 32) {
      int h = tid >> 3;
      float acc = 0.f;
      const float* row = p.v_w + tid * 32;
      #pragma unroll
      for (int c = 0; c < 32; ++c) acc = fmaf(row[c], sSS[h * 32 + c], acc);
      sOutV[tid] = acc / sSZ[h] + p.v_b[tid];
    }
    __syncthreads();
    // mod = o_w @ out + o_b ; z += coupling*mod ; mish
    if (tid < 32) {
      float acc = p.o_b[tid];
      const float* row = p.o_w + tid * 32;
      #pragma unroll
      for (int c = 0; c < 32; ++c) acc = fmaf(row[c], sOutV[c], acc);
      float zv2 = sZ[tid] + p.coupling[0] * acc;
      sZn[tid] = mish_f(zv2);
    }
    __syncthreads();
    // layer-norm over the 16 real / 16 imag components separately
    if (tid < 32) {
      int par = tid & 1;
      float m = 0.f;
      #pragma unroll
      for (int e = 0; e < 16; ++e) m += sZn[2 * e + par];
      m *= (1.f / 16.f);
      float v = 0.f;
      #pragma unroll
      for (int e = 0; e < 16; ++e) { float dd = sZn[2 * e + par] - m; v = fmaf(dd, dd, v); }
      v *= (1.f / 16.f);
      sZ[tid] = (sZn[tid] - m) * rsqrtf(v + 1e-5f) * p.norm_scale[0];
    }
    __syncthreads();

    if (iter != MSTEPS - 1) {
      compute_qar(p, tid, sZ, sQ, sA, sRel);
    } else {
      if (b == 0 && tid < 32) p.out[tid] = sZ[tid];
    }
  }
}

extern "C" void kernel_launch(void* const* d_in, const int* in_sizes, int n_in,
                              void* d_out, int out_size, void* d_ws, size_t ws_size,
                              hipStream_t stream) {
  PParams p;
  p.candidate  = (const float*)d_in[0];
  p.z_past     = (const float*)d_in[1];
  p.q_w = (const float*)d_in[2];  p.q_b = (const float*)d_in[3];
  p.k_w = (const float*)d_in[4];  p.k_b = (const float*)d_in[5];
  p.v_w = (const float*)d_in[6];  p.v_b = (const float*)d_in[7];
  p.o_w = (const float*)d_in[8];  p.o_b = (const float*)d_in[9];
  p.rel_bias   = (const float*)d_in[10];
  p.coupling   = (const float*)d_in[11];
  p.norm_scale = (const float*)d_in[12];
  p.out = (float*)d_out;
  p.ws  = (float*)d_ws;
  p.L   = in_sizes[1] / 32;

  // zero the per-iteration barrier counters (8 iters x 160 u32 = 5120 B);
  // captured as a graph node -> re-zeroed every replay. Partial tables need no
  // zeroing (fully overwritten each iteration before being read).
  hipMemsetAsync(d_ws, 0, 5120, stream);

  void* args[] = { &p };
  hipLaunchCooperativeKernel((const void*)photonic_kernel,
                             dim3(NB), dim3(BT), args, 0, stream);
}